// Round 1
// baseline (49.499 us; speedup 1.0000x reference)
//
#include <hip/hip_runtime.h>
#include <math.h>

#define BATCH 32
#define CHAN  512
#define HW    4096   // 64*64

// Kernel 1: per-(b,c) spatial mean. One block per plane, 256 threads,
// each thread loads 4 x float4 (16 floats) -> shuffle reduce -> LDS -> write.
__global__ __launch_bounds__(256) void mean_kernel(const float* __restrict__ x,
                                                   float* __restrict__ y) {
    int plane = blockIdx.x;                       // b*CHAN + c
    const float4* xp = (const float4*)(x + (size_t)plane * HW);
    int t = threadIdx.x;
    float s = 0.f;
#pragma unroll
    for (int i = 0; i < 4; ++i) {
        float4 v = xp[t + i * 256];
        s += v.x + v.y + v.z + v.w;
    }
    // wave(64) reduce
    for (int off = 32; off; off >>= 1) s += __shfl_down(s, off, 64);
    __shared__ float wsum[4];
    if ((t & 63) == 0) wsum[t >> 6] = s;
    __syncthreads();
    if (t == 0) {
        float tot = wsum[0] + wsum[1] + wsum[2] + wsum[3];
        y[plane] = tot * (1.0f / HW);
    }
}

// Kernel 2: per-batch conv1d(k=3, zero-pad) + sigmoid + top-3 (value desc,
// index asc on ties, matching lax.top_k). One block per batch row.
__global__ __launch_bounds__(512) void topk_kernel(const float* __restrict__ y,
                                                   const float* __restrict__ w,
                                                   int* __restrict__ idx_out) {
    int b = blockIdx.x;
    int c = threadIdx.x;
    __shared__ float ym[CHAN];
    __shared__ float sv[CHAN];
    __shared__ float rv[CHAN];
    __shared__ int   ri[CHAN];

    ym[c] = y[b * CHAN + c];
    __syncthreads();

    float w0 = w[0], w1 = w[1], w2 = w[2];
    float left  = (c > 0)        ? ym[c - 1] : 0.f;   // zero padding
    float right = (c < CHAN - 1) ? ym[c + 1] : 0.f;
    float s = w0 * left + w1 * ym[c] + w2 * right;    // lax conv = correlation (no flip)
    s = 1.f / (1.f + expf(-s));                        // sigmoid (monotonic, kept for exact ties)
    sv[c] = s;

    for (int pass = 0; pass < 3; ++pass) {
        __syncthreads();
        rv[c] = sv[c];
        ri[c] = c;
        __syncthreads();
        for (int stride = CHAN / 2; stride > 0; stride >>= 1) {
            if (c < stride) {
                float v2 = rv[c + stride];
                int   i2 = ri[c + stride];
                // prefer larger value; on exact tie prefer smaller index
                if (v2 > rv[c] || (v2 == rv[c] && i2 < ri[c])) {
                    rv[c] = v2;
                    ri[c] = i2;
                }
            }
            __syncthreads();
        }
        if (c == 0) {
            idx_out[b * 3 + pass] = ri[0];
            sv[ri[0]] = -1.0f;   // sigmoid >= 0, so -1 removes it from later passes
        }
    }
}

// Kernel 3: out[b,k,:,:] = x[b, idx[b,k], :, :]. One block per (b,k) plane.
__global__ __launch_bounds__(256) void gather_kernel(const float* __restrict__ x,
                                                     const int* __restrict__ idx,
                                                     float* __restrict__ out) {
    int blk = blockIdx.x;            // b*3 + k
    int b = blk / 3;
    int ch = idx[blk];
    const float4* src = (const float4*)(x + ((size_t)b * CHAN + ch) * HW);
    float4*       dst = (float4*)(out + (size_t)blk * HW);
    int t = threadIdx.x;
#pragma unroll
    for (int i = 0; i < 4; ++i) dst[t + i * 256] = src[t + i * 256];
}

extern "C" void kernel_launch(void* const* d_in, const int* in_sizes, int n_in,
                              void* d_out, int out_size, void* d_ws, size_t ws_size,
                              hipStream_t stream) {
    const float* x  = (const float*)d_in[0];   // (32,512,64,64)
    const float* cw = (const float*)d_in[1];   // (1,1,3)
    float* out = (float*)d_out;                // (32,3,64,64)

    float* y   = (float*)d_ws;                                   // 32*512 floats = 64 KB
    int*   idx = (int*)((char*)d_ws + BATCH * CHAN * sizeof(float)); // 96 ints

    mean_kernel<<<BATCH * CHAN, 256, 0, stream>>>(x, y);
    topk_kernel<<<BATCH, CHAN, 0, stream>>>(y, cw, idx);
    gather_kernel<<<BATCH * 3, 256, 0, stream>>>(x, idx, out);
}